// Round 15
// baseline (400.382 us; speedup 1.0000x reference)
//
#include <hip/hip_runtime.h>

#define T_NT 4
#define T_R  5
#define T_H  4
#define T_DK 32
#define T_HD 128
#define T_L  2
#define NCOL 1408   // 128 (k) + 640 (qt) + 640 (mtp)

typedef unsigned short u16;
typedef __bf16 bf8_t __attribute__((ext_vector_type(8)));
typedef float f4_t __attribute__((ext_vector_type(4)));

__device__ __forceinline__ float blo(unsigned u){
  union { float f; unsigned int i; } v; v.i = u << 16; return v.f;
}
__device__ __forceinline__ float bhi(unsigned u){
  union { float f; unsigned int i; } v; v.i = u & 0xffff0000u; return v.f;
}
__device__ __forceinline__ u16 f2bf(float f){
  union { float f; unsigned int i; } v; v.f = f;
  unsigned int x = v.i;
  return (u16)((x + 0x7fffu + ((x >> 16) & 1u)) >> 16);
}
__device__ __forceinline__ unsigned pk2(float a, float b){
  return (unsigned)f2bf(a) | ((unsigned)f2bf(b) << 16);
}
__device__ __forceinline__ float gelu_f(float x){
  float x3 = x*x*x;
  return 0.5f * x * (1.f + tanhf(0.7978845608028654f * (x + 0.044715f * x3)));
}
// mem-position -> logical col for the pair-packed layout (see k_qkvm epilogue)
__device__ __forceinline__ int perm_l(int m){
  return (m & ~31) | ((m & 4) << 2) | ((m & 24) >> 1) | (m & 3);
}

// ---------------- CSR / bucket build ----------------
__global__ void k_hist4(const int* __restrict__ key, int* __restrict__ cnt, int n){
  __shared__ int c[T_NT];
  int tid = threadIdx.x;
  if (tid < T_NT) c[tid] = 0;
  __syncthreads();
  int base = blockIdx.x*1024;
#pragma unroll
  for (int j=0;j<4;j++){
    int i = base + tid + j*256;
    if (i < n) atomicAdd(&c[key[i]], 1);
  }
  __syncthreads();
  if (tid < T_NT) atomicAdd(&cnt[tid], c[tid]);
}

// scatter + local toff derivation (block 0 publishes toff for downstream kernels)
__global__ void k_scatter2(const int* __restrict__ nt, const int* __restrict__ tcnt,
                           int* __restrict__ tcur, int* __restrict__ toff,
                           int* __restrict__ perm, int* __restrict__ iperm, int n){
  __shared__ int lc[T_NT], lb[T_NT], off_s[T_NT];
  int tid = threadIdx.x;
  if (tid < T_NT) lc[tid] = 0;
  __syncthreads();
  int base = blockIdx.x*1024;
  int t[4], lr[4];
#pragma unroll
  for (int j=0;j<4;j++){
    int i = base + tid + j*256;
    if (i < n){ t[j] = nt[i]; lr[j] = atomicAdd(&lc[t[j]], 1); }
    else t[j] = -1;
  }
  __syncthreads();
  if (tid == 0){
    int acc = 0;
#pragma unroll
    for (int tt = 0; tt < T_NT; ++tt){ off_s[tt] = acc; acc += tcnt[tt]; }
    if (blockIdx.x == 0){
#pragma unroll
      for (int tt = 0; tt < T_NT; ++tt) toff[tt] = off_s[tt];
      toff[T_NT] = acc;
    }
  }
  __syncthreads();
  if (tid < T_NT) lb[tid] = off_s[tid] + atomicAdd(&tcur[tid], lc[tid]);
  __syncthreads();
#pragma unroll
  for (int j=0;j<4;j++){
    if (t[j] >= 0){
      int node = base + tid + j*256;
      int pos = lb[t[j]] + lr[j];
      perm[pos] = node;
      iperm[node] = pos;
    }
  }
}

__global__ void k_deg(const int* __restrict__ dstp, const int* __restrict__ iperm,
                      int* __restrict__ degp, int* __restrict__ rank, int n){
  int i = blockIdx.x*256 + threadIdx.x;
  if (i < n) rank[i] = atomicAdd(&degp[(size_t)iperm[dstp[i]] << 4], 1);
}

__global__ void k_scanA(const int* __restrict__ degp, int* __restrict__ rp,
                        int* __restrict__ bsum, int n){
  __shared__ int buf[256];
  int tid = threadIdx.x;
  int i = blockIdx.x*256 + tid;
  int v = (i < n) ? degp[(size_t)i << 4] : 0;
  buf[tid] = v;
  __syncthreads();
  for (int off = 1; off < 256; off <<= 1){
    int add = (tid >= off) ? buf[tid - off] : 0;
    __syncthreads();
    buf[tid] += add;
    __syncthreads();
  }
  if (i < n) rp[i] = buf[tid] - v;
  if (tid == 255) bsum[blockIdx.x] = buf[255];
}
__global__ void k_scanB(int* __restrict__ bsum, int nb){
  __shared__ int buf[1024];
  int tid = threadIdx.x;
  int v = (tid < nb) ? bsum[tid] : 0;
  buf[tid] = v;
  __syncthreads();
  for (int off = 1; off < 1024; off <<= 1){
    int add = (tid >= off) ? buf[tid - off] : 0;
    __syncthreads();
    buf[tid] += add;
    __syncthreads();
  }
  if (tid < nb) bsum[tid] = buf[tid] - v;
}
__global__ void k_scanC(int* __restrict__ rp, const int* __restrict__ bsum,
                        int n, int E){
  int i = blockIdx.x*256 + threadIdx.x;
  if (i < n) rp[i] += bsum[blockIdx.x];
  if (i == 0) rp[n] = E;
}

__global__ void k_fill2(const int* __restrict__ srcp, const int* __restrict__ dstp,
                        const int* __restrict__ etp, const int* __restrict__ iperm,
                        const int* __restrict__ rp, const int* __restrict__ rank,
                        int* __restrict__ packed, int n){
  int i = blockIdx.x*256 + threadIdx.x;
  if (i < n){
    int d = iperm[dstp[i]];
    packed[rp[d] + rank[i]] = iperm[srcp[i]] | (etp[i] << 17);
  }
}

// ---------------- combined-weight prep ----------------
__global__ void k_prepmisc(const float* __restrict__ kw, const float* __restrict__ kb,
                           const float* __restrict__ qb, const float* __restrict__ vb,
                           const float* __restrict__ rel_att, const float* __restrict__ rel_msg,
                           const float* __restrict__ rel_pri,
                           u16* __restrict__ Ball, float* __restrict__ biasall)
{
  const float isd = 0.17677669529663687f;
  int idx = blockIdx.x*256 + threadIdx.x;
  if (idx < T_L*T_NT*T_HD*T_HD){
    int col = idx & 127, k = (idx >> 7) & 127, lt = idx >> 14;
    Ball[((size_t)lt*NCOL + col)*T_HD + k] = f2bf(kw[((size_t)lt*T_HD + k)*T_HD + col]);
    if (k == 0) biasall[(size_t)lt*NCOL + col] = kb[(size_t)lt*T_HD + col];
    return;
  }
  int b = idx - T_L*T_NT*T_HD*T_HD;
  if (b >= T_L*T_NT*1280) return;
  int lt = b / 1280, cc = b % 1280;
  int l = lt >> 2;
  int qv = cc >= 640, rem = cc - qv*640;
  int r = rem >> 7, hd = rem & 127, h = hd >> 5, o = hd & 31;
  float s = 0.f;
  if (!qv){
    const float* Ar = rel_att + ((((size_t)l*T_R + r)*T_H + h)*T_DK + o)*T_DK;
    const float* qbr = qb + (size_t)lt*T_HD + h*T_DK;
#pragma unroll
    for (int j = 0; j < 32; ++j) s += qbr[j] * Ar[j];
    s *= rel_pri[((size_t)l*T_R + r)*T_H + h] * isd;
  } else {
    const float* Mr = rel_msg + (((size_t)l*T_R + r)*T_H + h)*T_DK*T_DK + o;
    const float* vbr = vb + (size_t)lt*T_HD + h*T_DK;
#pragma unroll
    for (int i = 0; i < 32; ++i) s += vbr[i] * Mr[i*T_DK];
  }
  biasall[(size_t)lt*NCOL + 128 + qv*640 + r*128 + h*32 + o] = s;
}

__global__ __launch_bounds__(256)
void k_prepqv(const float* __restrict__ qw, const float* __restrict__ vw,
              const float* __restrict__ rel_att, const float* __restrict__ rel_msg,
              const float* __restrict__ rel_pri, u16* __restrict__ Ball)
{
  __shared__ float Ws[T_HD*33];
  __shared__ float As_[T_R*32*36];
  const float isd = 0.17677669529663687f;
  int h = blockIdx.x & 3, qv = blockIdx.x >> 2;
  int t = blockIdx.y, l = blockIdx.z;
  int lt = l*T_NT + t;
  int tid = threadIdx.x;
  const float* W = (qv ? vw : qw) + (size_t)lt*T_HD*T_HD;
  const float* rel = (qv ? rel_msg : rel_att);
#pragma unroll
  for (int i = 0; i < 16; ++i){
    int idx = tid + i*256;
    int j = idx & 31, k = idx >> 5;
    Ws[k*33 + j] = W[(size_t)k*T_HD + h*T_DK + j];
  }
#pragma unroll
  for (int i = 0; i < 20; ++i){
    int idx = tid + i*256;
    int bcol = idx & 31, a = (idx >> 5) & 31, r = idx >> 10;
    float wv = rel[((((size_t)l*T_R + r)*T_H + h)*T_DK + a)*T_DK + bcol];
    if (qv) As_[r*1152 + bcol*36 + a] = wv;
    else    As_[r*1152 + a*36 + bcol] = wv;
  }
  __syncthreads();
  int k = tid & 127, io = tid >> 7;
  float Wrow[32];
#pragma unroll
  for (int c = 0; c < 32; ++c) Wrow[c] = Ws[k*33 + c];
  for (int r = 0; r < T_R; ++r){
    float scale = qv ? 1.f : rel_pri[((size_t)l*T_R + r)*T_H + h] * isd;
#pragma unroll
    for (int i2 = 0; i2 < 16; ++i2){
      int o = i2*2 + io;
      const float4* ap = (const float4*)&As_[r*1152 + o*36];
      float acc = 0.f;
#pragma unroll
      for (int c4 = 0; c4 < 8; ++c4){
        float4 a4 = ap[c4];
        acc += Wrow[c4*4+0]*a4.x + Wrow[c4*4+1]*a4.y + Wrow[c4*4+2]*a4.z + Wrow[c4*4+3]*a4.w;
      }
      int col = 128 + qv*640 + r*128 + h*32 + o;
      Ball[((size_t)lt*NCOL + col)*T_HD + k] = f2bf(acc*scale);
    }
  }
}

// bf16 transposed weights for the FFN MFMA kernels
__global__ void k_prepw2(const float* __restrict__ adapt_w, const float* __restrict__ aw,
                         u16* __restrict__ adaptT, u16* __restrict__ awT)
{
  int idx = blockIdx.x*256 + threadIdx.x;
  if (idx < T_NT*T_HD*T_HD){
    int k = idx & 127, col = (idx >> 7) & 127, t = idx >> 14;
    adaptT[idx] = f2bf(adapt_w[((size_t)t*T_HD + k)*T_HD + col]);
  } else {
    int j = idx - T_NT*T_HD*T_HD;
    if (j >= T_L*T_NT*T_HD*T_HD) return;
    int k = j & 127, col = (j >> 7) & 127, lt = j >> 14;
    awT[j] = f2bf(aw[((size_t)lt*T_HD + perm_l(k))*T_HD + col]);
  }
}

// ---------------- fused per-type MFMA GEMM: h16(bucket) -> {kB, qt, mtp}(bucket) ----------------
__global__ __launch_bounds__(256)
void k_qkvm(const u16* __restrict__ X16, const int* __restrict__ toff,
            const u16* __restrict__ Ball, const float* __restrict__ biasall,
            u16* __restrict__ kB, u16* __restrict__ qt, u16* __restrict__ mtp)
{
  __shared__ u16 As[64*128];
  int t = blockIdx.y;
  int z = blockIdx.z;
  int lo = toff[t], cnt = toff[t+1] - lo;
  int base = (int)blockIdx.x * 64;
  if (base >= cnt) return;
  int tid = threadIdx.x;
#pragma unroll
  for (int it = 0; it < 4; ++it){
    int chunk = tid + it*256;
    int row = chunk >> 4, c8 = (chunk & 15) << 3;
    uint4 o = make_uint4(0,0,0,0);
    if (base + row < cnt)
      o = *(const uint4*)&X16[(size_t)(lo + base + row)*T_HD + c8];
    int off16 = (row*128 + c8) ^ ((row & 7) << 3);
    *(uint4*)&As[off16] = o;
  }
  __syncthreads();

  int wid = tid >> 6, lane = tid & 63;
  int lr = lane & 15, lg = lane >> 4;
  bf8_t a[4][4];
#pragma unroll
  for (int rs = 0; rs < 4; ++rs)
#pragma unroll
    for (int kk = 0; kk < 4; ++kk){
      int row = rs*16 + lr;
      int off16 = (row*128 + kk*32 + lg*8) ^ ((row & 7) << 3);
      a[rs][kk] = *(const bf8_t*)&As[off16];
    }

  const u16* Bt = Ball + (size_t)t * NCOL * T_HD;
  const float* biast = biasall + (size_t)t * NCOL;

  int ci_end = z ? 44 : 22;
  for (int ci = z*22 + wid; ci < ci_end; ci += 4){
    int c0 = ci*2;
    int col0 = c0*16 + lr;
    const u16* bp0 = Bt + (size_t)col0*T_HD + lg*8;
    const u16* bp1 = bp0 + (size_t)16*T_HD;
    bf8_t b00 = *(const bf8_t*)(bp0);
    bf8_t b01 = *(const bf8_t*)(bp0 + 32);
    bf8_t b02 = *(const bf8_t*)(bp0 + 64);
    bf8_t b03 = *(const bf8_t*)(bp0 + 96);
    bf8_t b10 = *(const bf8_t*)(bp1);
    bf8_t b11 = *(const bf8_t*)(bp1 + 32);
    bf8_t b12 = *(const bf8_t*)(bp1 + 64);
    bf8_t b13 = *(const bf8_t*)(bp1 + 96);
    f4_t acc0[4], acc1[4];
#pragma unroll
    for (int rs = 0; rs < 4; ++rs){ acc0[rs] = (f4_t){0.f,0.f,0.f,0.f}; acc1[rs] = (f4_t){0.f,0.f,0.f,0.f}; }
#pragma unroll
    for (int rs = 0; rs < 4; ++rs){
      acc0[rs] = __builtin_amdgcn_mfma_f32_16x16x32_bf16(b00, a[rs][0], acc0[rs], 0, 0, 0);
      acc0[rs] = __builtin_amdgcn_mfma_f32_16x16x32_bf16(b01, a[rs][1], acc0[rs], 0, 0, 0);
      acc0[rs] = __builtin_amdgcn_mfma_f32_16x16x32_bf16(b02, a[rs][2], acc0[rs], 0, 0, 0);
      acc0[rs] = __builtin_amdgcn_mfma_f32_16x16x32_bf16(b03, a[rs][3], acc0[rs], 0, 0, 0);
      acc1[rs] = __builtin_amdgcn_mfma_f32_16x16x32_bf16(b10, a[rs][0], acc1[rs], 0, 0, 0);
      acc1[rs] = __builtin_amdgcn_mfma_f32_16x16x32_bf16(b11, a[rs][1], acc1[rs], 0, 0, 0);
      acc1[rs] = __builtin_amdgcn_mfma_f32_16x16x32_bf16(b12, a[rs][2], acc1[rs], 0, 0, 0);
      acc1[rs] = __builtin_amdgcn_mfma_f32_16x16x32_bf16(b13, a[rs][3], acc1[rs], 0, 0, 0);
    }
    float4 bias0 = *(const float4*)&biast[c0*16 + lg*4];
    float4 bias1 = *(const float4*)&biast[c0*16 + 16 + lg*4];
    int mco = ci*32 + lg*8;
    u16* dst; int cofs, stride;
    if (ci < 4)       { dst = kB;  cofs = mco;        stride = T_HD; }
    else if (ci < 24) { dst = qt;  cofs = mco - 128;  stride = T_R*T_HD; }
    else              { dst = mtp; cofs = mco - 768;  stride = T_R*T_HD; }
#pragma unroll
    for (int rs = 0; rs < 4; ++rs){
      int nl = rs*16 + lr;
      if (base + nl < cnt){
        uint4 o;
        o.x = pk2(acc0[rs][0] + bias0.x, acc0[rs][1] + bias0.y);
        o.y = pk2(acc0[rs][2] + bias0.z, acc0[rs][3] + bias0.w);
        o.z = pk2(acc1[rs][0] + bias1.x, acc1[rs][1] + bias1.y);
        o.w = pk2(acc1[rs][2] + bias1.z, acc1[rs][3] + bias1.w);
        *(uint4*)&dst[(size_t)(lo + base + nl)*stride + cofs] = o;
      }
    }
  }
}

// ---------------- MFMA FFN: adapt (MODE 1) and update (MODE 3) ----------------
// SHADOW: also write bf16 copy of the output (for the next k_qkvm's A reads)
template<int MODE, int GIN, int SOUT, int SHADOW>
__global__ __launch_bounds__(256)
void k_ffn(const float* __restrict__ X, const int* __restrict__ tperm,
           const int* __restrict__ toff, const u16* __restrict__ WT,
           const float* __restrict__ Bi, float* __restrict__ outv,
           u16* __restrict__ out16,
           const float* __restrict__ h_in, const float* __restrict__ skipv)
{
  __shared__ u16 As[64*128];
  __shared__ int rows_s[64];
  int t = blockIdx.y;
  int lo = toff[t], cnt = toff[t+1] - lo;
  int base = (int)blockIdx.x * 64;
  if (base >= cnt) return;
  int tid = threadIdx.x;
  if (GIN || SOUT){
    if (tid < 64) rows_s[tid] = (base + tid < cnt) ? tperm[lo + base + tid] : 0;
    __syncthreads();
  }
#pragma unroll
  for (int it = 0; it < 4; ++it){
    int chunk = tid + it*256;
    int row = chunk >> 4, c8 = (chunk & 15) << 3;
    uint4 o = make_uint4(0,0,0,0);
    if (base + row < cnt){
      const float* src = GIN ? (X + (size_t)rows_s[row]*T_HD + c8)
                             : (X + (size_t)(lo + base + row)*T_HD + c8);
      float4 f0 = *(const float4*)src;
      float4 f1 = *(const float4*)(src + 4);
      if (MODE == 3){
        f0.x = gelu_f(f0.x); f0.y = gelu_f(f0.y); f0.z = gelu_f(f0.z); f0.w = gelu_f(f0.w);
        f1.x = gelu_f(f1.x); f1.y = gelu_f(f1.y); f1.z = gelu_f(f1.z); f1.w = gelu_f(f1.w);
      }
      o.x = pk2(f0.x, f0.y);
      o.y = pk2(f0.z, f0.w);
      o.z = pk2(f1.x, f1.y);
      o.w = pk2(f1.z, f1.w);
    }
    int off16 = (row*128 + c8) ^ ((row & 7) << 3);
    *(uint4*)&As[off16] = o;
  }
  __syncthreads();

  int wid = tid >> 6, lane = tid & 63;
  int lr = lane & 15, lg = lane >> 4;
  bf8_t a[4][4];
#pragma unroll
  for (int rs = 0; rs < 4; ++rs)
#pragma unroll
    for (int kk = 0; kk < 4; ++kk){
      int row = rs*16 + lr;
      int off16 = (row*128 + kk*32 + lg*8) ^ ((row & 7) << 3);
      a[rs][kk] = *(const bf8_t*)&As[off16];
    }

  const u16* Wt = WT + (size_t)t * T_HD * T_HD;
  float sk = 0.f;
  if (MODE == 3) sk = 1.f / (1.f + __expf(-skipv[t]));

  for (int c = wid; c < 8; c += 4){
    const u16* bp = Wt + (size_t)(c*16 + lr)*T_HD + lg*8;
    bf8_t b0 = *(const bf8_t*)(bp);
    bf8_t b1 = *(const bf8_t*)(bp + 32);
    bf8_t b2 = *(const bf8_t*)(bp + 64);
    bf8_t b3 = *(const bf8_t*)(bp + 96);
    f4_t acc[4];
#pragma unroll
    for (int rs = 0; rs < 4; ++rs) acc[rs] = (f4_t){0.f,0.f,0.f,0.f};
#pragma unroll
    for (int rs = 0; rs < 4; ++rs){
      acc[rs] = __builtin_amdgcn_mfma_f32_16x16x32_bf16(b0, a[rs][0], acc[rs], 0, 0, 0);
      acc[rs] = __builtin_amdgcn_mfma_f32_16x16x32_bf16(b1, a[rs][1], acc[rs], 0, 0, 0);
      acc[rs] = __builtin_amdgcn_mfma_f32_16x16x32_bf16(b2, a[rs][2], acc[rs], 0, 0, 0);
      acc[rs] = __builtin_amdgcn_mfma_f32_16x16x32_bf16(b3, a[rs][3], acc[rs], 0, 0, 0);
    }
    int cc = c*16 + lg*4;
    float4 bias4 = *(const float4*)&Bi[t*T_HD + cc];
#pragma unroll
    for (int rs = 0; rs < 4; ++rs){
      int nl = rs*16 + lr;
      if (base + nl < cnt){
        float4 vv;
        vv.x = acc[rs][0] + bias4.x;
        vv.y = acc[rs][1] + bias4.y;
        vv.z = acc[rs][2] + bias4.z;
        vv.w = acc[rs][3] + bias4.w;
        if (MODE == 1){
          vv.x = tanhf(vv.x); vv.y = tanhf(vv.y); vv.z = tanhf(vv.z); vv.w = tanhf(vv.w);
        }
        if (MODE == 3){
          float4 hr = *(const float4*)&h_in[(size_t)(lo + base + nl)*T_HD + cc];
          float osk = 1.f - sk;
          vv.x = vv.x*sk + hr.x*osk;
          vv.y = vv.y*sk + hr.y*osk;
          vv.z = vv.z*sk + hr.z*osk;
          vv.w = vv.w*sk + hr.w*osk;
        }
        size_t opos = SOUT ? (size_t)rows_s[nl] : (size_t)(lo + base + nl);
        *(float4*)&outv[opos*T_HD + cc] = vv;
        if (SHADOW){
          uint2 s16;
          s16.x = pk2(vv.x, vv.y);
          s16.y = pk2(vv.z, vv.w);
          *(uint2*)&out16[(size_t)(lo + base + nl)*T_HD + cc] = s16;
        }
      }
    }
  }
}

// ---------------- per-dst edge attention (single-state, deferred-max) ----------------
__global__ __launch_bounds__(256)
void k_edge_attn2(const u16* __restrict__ kB, const u16* __restrict__ qt,
                  const u16* __restrict__ mtp, const int* __restrict__ rp,
                  const int* __restrict__ packed, float* __restrict__ resb, int n)
{
  int lane = threadIdx.x & 63;
  int wid = (int)blockIdx.x * (blockDim.x >> 6) + (threadIdx.x >> 6);
  int nw = (int)gridDim.x * (blockDim.x >> 6);
  int l2 = lane << 1;
  for (int dst = wid; dst < n; dst += nw){
    int e0 = rp[dst], e1 = rp[dst+1];
    if (e0 == e1){
      *(float2*)&resb[(size_t)dst*T_HD + l2] = make_float2(0.f, 0.f);
      continue;
    }
    const u16* qrow = qt + (size_t)dst*(T_R*T_HD) + l2;
    float m = -1e30f, d = 0.f, a0 = 0.f, a1 = 0.f;
    int ei = e0;
    for (; ei + 1 < e1; ei += 2){
      int pka = packed[ei], pkb = packed[ei+1];
      int sa = pka & 131071, ra = pka >> 17;
      int sb = pkb & 131071, rb = pkb >> 17;
      unsigned ka  = *(const unsigned*)&kB[(sa << 7) + l2];
      unsigned kbv = *(const unsigned*)&kB[(sb << 7) + l2];
      unsigned qa = *(const unsigned*)&qrow[ra << 7];
      unsigned qb = *(const unsigned*)&qrow[rb << 7];
      unsigned ma = *(const unsigned*)&mtp[((sa*T_R + ra) << 7) + l2];
      unsigned mb = *(const unsigned*)&mtp[((sb*T_R + rb) << 7) + l2];
      float pa = blo(qa)*blo(ka) + bhi(qa)*bhi(ka);
      float pb = blo(qb)*blo(kbv) + bhi(qb)*bhi(kbv);
      pa += __shfl_xor(pa, 1);  pb += __shfl_xor(pb, 1);
      pa += __shfl_xor(pa, 2);  pb += __shfl_xor(pb, 2);
      pa += __shfl_xor(pa, 4);  pb += __shfl_xor(pb, 4);
      pa += __shfl_xor(pa, 8);  pb += __shfl_xor(pb, 8);
      float pmax = fmaxf(pa, pb);
      if (__any(pmax > m + 8.f)){
        float mn = fmaxf(m, pmax);
        float sc = __expf(m - mn);
        d *= sc; a0 *= sc; a1 *= sc;
        m = mn;
      }
      float wA = __expf(pa - m), wB = __expf(pb - m);
      d  += wA + wB;
      a0 += wA*blo(ma) + wB*blo(mb);
      a1 += wA*bhi(ma) + wB*bhi(mb);
    }
    if (ei < e1){
      int pka = packed[ei];
      int sa = pka & 131071, ra = pka >> 17;
      unsigned ka = *(const unsigned*)&kB[(sa << 7) + l2];
      unsigned qa = *(const unsigned*)&qrow[ra << 7];
      unsigned ma = *(const unsigned*)&mtp[((sa*T_R + ra) << 7) + l2];
      float pa = blo(qa)*blo(ka) + bhi(qa)*bhi(ka);
      pa += __shfl_xor(pa, 1);
      pa += __shfl_xor(pa, 2);
      pa += __shfl_xor(pa, 4);
      pa += __shfl_xor(pa, 8);
      if (__any(pa > m + 8.f)){
        float mn = fmaxf(m, pa);
        float sc = __expf(m - mn);
        d *= sc; a0 *= sc; a1 *= sc;
        m = mn;
      }
      float wA = __expf(pa - m);
      d  += wA;
      a0 += wA*blo(ma);
      a1 += wA*bhi(ma);
    }
    float inv = 1.f / fmaxf(d, 1e-9f);
    *(float2*)&resb[(size_t)dst*T_HD + l2] = make_float2(a0*inv, a1*inv);
  }
}

extern "C" void kernel_launch(void* const* d_in, const int* in_sizes, int n_in,
                              void* d_out, int out_size, void* d_ws, size_t ws_size,
                              hipStream_t stream)
{
  const float* node_feature = (const float*)d_in[0];
  const int* node_type    = (const int*)d_in[1];
  const int* edge_index   = (const int*)d_in[3];
  const int* edge_type    = (const int*)d_in[4];
  const float* adapt_w = (const float*)d_in[5];
  const float* adapt_b = (const float*)d_in[6];
  const float* kw = (const float*)d_in[7];
  const float* kb = (const float*)d_in[8];
  const float* qw = (const float*)d_in[9];
  const float* qb = (const float*)d_in[10];
  const float* vw = (const float*)d_in[11];
  const float* vb = (const float*)d_in[12];
  const float* aw = (const float*)d_in[13];
  const float* ab = (const float*)d_in[14];
  const float* rel_pri = (const float*)d_in[15];
  const float* rel_att = (const float*)d_in[16];
  const float* rel_msg = (const float*)d_in[17];
  const float* skipp   = (const float*)d_in[18];

  const int N = in_sizes[1];
  const int E = in_sizes[4];
  const int* srcp = edge_index;
  const int* dstp = edge_index + E;

  char* p = (char*)d_ws;
  auto take = [&](size_t bytes)->char*{
    char* r = p; p += (bytes + 255) & ~(size_t)255; return r;
  };
  float* h0   = (float*)take((size_t)N*T_HD*4);
  u16*  h16   = (u16*) take((size_t)N*T_HD*2);
  float* resb = (float*)take((size_t)N*T_HD*4);
  u16*  kB    = (u16*) take((size_t)N*T_HD*2);
  u16*  qt    = (u16*) take((size_t)N*T_R*T_HD*2);
  u16*  mtp   = (u16*) take((size_t)N*T_R*T_HD*2);
  u16*  Ball  = (u16*) take((size_t)T_L*T_NT*NCOL*T_HD*2);
  float* biasall = (float*)take((size_t)T_L*T_NT*NCOL*4);
  u16*  adaptT = (u16*)take((size_t)T_NT*T_HD*T_HD*2);
  u16*  awT    = (u16*)take((size_t)T_L*T_NT*T_HD*T_HD*2);
  int* degp   = (int*) take((size_t)N*16*4);
  int* rp     = (int*) take(((size_t)N+1)*4);
  int* rank   = (int*) take((size_t)E*4);
  int* packed = (int*) take((size_t)E*4);
  int* tcnt   = (int*) take(256);
  int* toff   = (int*) take(256);
  int* tcur   = (int*) take(256);
  int* bsum   = (int*) take(1024);
  int* tperm  = (int*) take((size_t)N*4);
  int* iperm  = (int*) take((size_t)N*4);

  hipMemsetAsync(degp, 0, (size_t)N*16*4, stream);
  hipMemsetAsync(tcnt, 0, 256, stream);
  hipMemsetAsync(tcur, 0, 256, stream);

  int nb_n4 = (N + 1023)/1024, nb_e = (E + 255)/256;
  int nb_s  = (N + 255)/256;
  k_hist4<<<nb_n4, 256, 0, stream>>>(node_type, tcnt, N);
  k_scatter2<<<nb_n4, 256, 0, stream>>>(node_type, tcnt, tcur, toff, tperm, iperm, N);
  k_deg<<<nb_e, 256, 0, stream>>>(dstp, iperm, degp, rank, E);
  k_scanA<<<nb_s, 256, 0, stream>>>(degp, rp, bsum, N);
  k_scanB<<<1, 1024, 0, stream>>>(bsum, nb_s);
  k_scanC<<<nb_s, 256, 0, stream>>>(rp, bsum, N, E);
  k_fill2<<<nb_e, 256, 0, stream>>>(srcp, dstp, edge_type, iperm, rp, rank, packed, E);

  int misc_total = T_L*T_NT*T_HD*T_HD + T_L*T_NT*1280;
  k_prepmisc<<<(misc_total + 255)/256, 256, 0, stream>>>(
      kw, kb, qb, vb, rel_att, rel_msg, rel_pri, Ball, biasall);
  k_prepqv<<<dim3(8, T_NT, T_L), 256, 0, stream>>>(
      qw, vw, rel_att, rel_msg, rel_pri, Ball);
  int w2_total = T_NT*T_HD*T_HD + T_L*T_NT*T_HD*T_HD;
  k_prepw2<<<(w2_total + 255)/256, 256, 0, stream>>>(adapt_w, aw, adaptT, awT);

  dim3 gg((N + 63)/64, T_NT);
  dim3 gq((N + 63)/64, T_NT, 2);
  // adapt: h0 (f32) + h16 (bf16 shadow for qkvm)
  k_ffn<1,1,0,1><<<gg, 256, 0, stream>>>(node_feature, tperm, toff, adaptT, adapt_b,
                                         h0, h16, nullptr, nullptr);

  for (int l = 0; l < T_L; ++l){
    size_t bo = (size_t)l * T_NT * T_HD;
    k_qkvm<<<gq, 256, 0, stream>>>(h16, toff,
        Ball + (size_t)l*T_NT*NCOL*T_HD, biasall + (size_t)l*T_NT*NCOL,
        kB, qt, mtp);
    k_edge_attn2<<<2048, 256, 0, stream>>>(kB, qt, mtp, rp, packed, resb, N);
    if (l == T_L - 1)
      k_ffn<3,0,1,0><<<gg, 256, 0, stream>>>(resb, tperm, toff,
          awT + (size_t)l*T_NT*T_HD*T_HD, ab + bo, (float*)d_out, nullptr, h0, skipp + l*T_NT);
    else
      k_ffn<3,0,0,1><<<gg, 256, 0, stream>>>(resb, tperm, toff,
          awT + (size_t)l*T_NT*T_HD*T_HD, ab + bo, h0, h16, h0, skipp + l*T_NT);
  }
}

// Round 16
// 389.942 us; speedup vs baseline: 1.0268x; 1.0268x over previous
//
#include <hip/hip_runtime.h>

#define T_NT 4
#define T_R  5
#define T_H  4
#define T_DK 32
#define T_HD 128
#define T_L  2
#define NCOL 1408   // 128 (k) + 640 (qt) + 640 (mtp)

typedef unsigned short u16;
typedef __bf16 bf8_t __attribute__((ext_vector_type(8)));
typedef float f4_t __attribute__((ext_vector_type(4)));

__device__ __forceinline__ float blo(unsigned u){
  union { float f; unsigned int i; } v; v.i = u << 16; return v.f;
}
__device__ __forceinline__ float bhi(unsigned u){
  union { float f; unsigned int i; } v; v.i = u & 0xffff0000u; return v.f;
}
__device__ __forceinline__ u16 f2bf(float f){
  union { float f; unsigned int i; } v; v.f = f;
  unsigned int x = v.i;
  return (u16)((x + 0x7fffu + ((x >> 16) & 1u)) >> 16);
}
__device__ __forceinline__ unsigned pk2(float a, float b){
  return (unsigned)f2bf(a) | ((unsigned)f2bf(b) << 16);
}
__device__ __forceinline__ float gelu_f(float x){
  float x3 = x*x*x;
  return 0.5f * x * (1.f + tanhf(0.7978845608028654f * (x + 0.044715f * x3)));
}
// mem-position -> logical col for the pair-packed layout (see k_qkvm epilogue)
__device__ __forceinline__ int perm_l(int m){
  return (m & ~31) | ((m & 4) << 2) | ((m & 24) >> 1) | (m & 3);
}

// ---------------- CSR / bucket build ----------------
__global__ void k_hist4(const int* __restrict__ key, int* __restrict__ cnt, int n){
  __shared__ int c[T_NT];
  int tid = threadIdx.x;
  if (tid < T_NT) c[tid] = 0;
  __syncthreads();
  int base = blockIdx.x*1024;
#pragma unroll
  for (int j=0;j<4;j++){
    int i = base + tid + j*256;
    if (i < n) atomicAdd(&c[key[i]], 1);
  }
  __syncthreads();
  if (tid < T_NT) atomicAdd(&cnt[tid], c[tid]);
}

__global__ void k_toff(const int* __restrict__ cnt, int* __restrict__ off, int* __restrict__ tcur){
  if (threadIdx.x == 0){
    off[0] = 0;
    for (int t = 0; t < T_NT; ++t) off[t+1] = off[t] + cnt[t];
    for (int t = 0; t < T_NT; ++t) tcur[t] = off[t];
  }
}

__global__ void k_scatter2(const int* __restrict__ nt, int* __restrict__ tcur,
                           int* __restrict__ perm, int* __restrict__ iperm, int n){
  __shared__ int lc[T_NT], lb[T_NT];
  int tid = threadIdx.x;
  if (tid < T_NT) lc[tid] = 0;
  __syncthreads();
  int base = blockIdx.x*1024;
  int t[4], lr[4];
#pragma unroll
  for (int j=0;j<4;j++){
    int i = base + tid + j*256;
    if (i < n){ t[j] = nt[i]; lr[j] = atomicAdd(&lc[t[j]], 1); }
    else t[j] = -1;
  }
  __syncthreads();
  if (tid < T_NT) lb[tid] = atomicAdd(&tcur[tid], lc[tid]);
  __syncthreads();
#pragma unroll
  for (int j=0;j<4;j++){
    if (t[j] >= 0){
      int node = base + tid + j*256;
      int pos = lb[t[j]] + lr[j];
      perm[pos] = node;
      iperm[node] = pos;
    }
  }
}

__global__ void k_deg(const int* __restrict__ dstp, const int* __restrict__ iperm,
                      int* __restrict__ degp, int* __restrict__ rank, int n){
  int i = blockIdx.x*256 + threadIdx.x;
  if (i < n) rank[i] = atomicAdd(&degp[(size_t)iperm[dstp[i]] << 4], 1);
}

__global__ void k_scanA(const int* __restrict__ degp, int* __restrict__ rp,
                        int* __restrict__ bsum, int n){
  __shared__ int buf[256];
  int tid = threadIdx.x;
  int i = blockIdx.x*256 + tid;
  int v = (i < n) ? degp[(size_t)i << 4] : 0;
  buf[tid] = v;
  __syncthreads();
  for (int off = 1; off < 256; off <<= 1){
    int add = (tid >= off) ? buf[tid - off] : 0;
    __syncthreads();
    buf[tid] += add;
    __syncthreads();
  }
  if (i < n) rp[i] = buf[tid] - v;
  if (tid == 255) bsum[blockIdx.x] = buf[255];
}
__global__ void k_scanB(int* __restrict__ bsum, int nb){
  __shared__ int buf[1024];
  int tid = threadIdx.x;
  int v = (tid < nb) ? bsum[tid] : 0;
  buf[tid] = v;
  __syncthreads();
  for (int off = 1; off < 1024; off <<= 1){
    int add = (tid >= off) ? buf[tid - off] : 0;
    __syncthreads();
    buf[tid] += add;
    __syncthreads();
  }
  if (tid < nb) bsum[tid] = buf[tid] - v;
}
__global__ void k_scanC(int* __restrict__ rp, const int* __restrict__ bsum,
                        int n, int E){
  int i = blockIdx.x*256 + threadIdx.x;
  if (i < n) rp[i] += bsum[blockIdx.x];
  if (i == 0) rp[n] = E;
}

__global__ void k_fill2(const int* __restrict__ srcp, const int* __restrict__ dstp,
                        const int* __restrict__ etp, const int* __restrict__ iperm,
                        const int* __restrict__ rp, const int* __restrict__ rank,
                        int* __restrict__ packed, int n){
  int i = blockIdx.x*256 + threadIdx.x;
  if (i < n){
    int d = iperm[dstp[i]];
    packed[rp[d] + rank[i]] = iperm[srcp[i]] | (etp[i] << 17);
  }
}

// ---------------- combined-weight prep ----------------
__global__ void k_prepmisc(const float* __restrict__ kw, const float* __restrict__ kb,
                           const float* __restrict__ qb, const float* __restrict__ vb,
                           const float* __restrict__ rel_att, const float* __restrict__ rel_msg,
                           const float* __restrict__ rel_pri,
                           u16* __restrict__ Ball, float* __restrict__ biasall)
{
  const float isd = 0.17677669529663687f;
  int idx = blockIdx.x*256 + threadIdx.x;
  if (idx < T_L*T_NT*T_HD*T_HD){
    int col = idx & 127, k = (idx >> 7) & 127, lt = idx >> 14;
    Ball[((size_t)lt*NCOL + col)*T_HD + k] = f2bf(kw[((size_t)lt*T_HD + k)*T_HD + col]);
    if (k == 0) biasall[(size_t)lt*NCOL + col] = kb[(size_t)lt*T_HD + col];
    return;
  }
  int b = idx - T_L*T_NT*T_HD*T_HD;
  if (b >= T_L*T_NT*1280) return;
  int lt = b / 1280, cc = b % 1280;
  int l = lt >> 2;
  int qv = cc >= 640, rem = cc - qv*640;
  int r = rem >> 7, hd = rem & 127, h = hd >> 5, o = hd & 31;
  float s = 0.f;
  if (!qv){
    const float* Ar = rel_att + ((((size_t)l*T_R + r)*T_H + h)*T_DK + o)*T_DK;
    const float* qbr = qb + (size_t)lt*T_HD + h*T_DK;
#pragma unroll
    for (int j = 0; j < 32; ++j) s += qbr[j] * Ar[j];
    s *= rel_pri[((size_t)l*T_R + r)*T_H + h] * isd;
  } else {
    const float* Mr = rel_msg + (((size_t)l*T_R + r)*T_H + h)*T_DK*T_DK + o;
    const float* vbr = vb + (size_t)lt*T_HD + h*T_DK;
#pragma unroll
    for (int i = 0; i < 32; ++i) s += vbr[i] * Mr[i*T_DK];
  }
  biasall[(size_t)lt*NCOL + 128 + qv*640 + r*128 + h*32 + o] = s;
}

__global__ __launch_bounds__(256)
void k_prepqv(const float* __restrict__ qw, const float* __restrict__ vw,
              const float* __restrict__ rel_att, const float* __restrict__ rel_msg,
              const float* __restrict__ rel_pri, u16* __restrict__ Ball)
{
  __shared__ float Ws[T_HD*33];
  __shared__ float As_[T_R*32*36];
  const float isd = 0.17677669529663687f;
  int h = blockIdx.x & 3, qv = blockIdx.x >> 2;
  int t = blockIdx.y, l = blockIdx.z;
  int lt = l*T_NT + t;
  int tid = threadIdx.x;
  const float* W = (qv ? vw : qw) + (size_t)lt*T_HD*T_HD;
  const float* rel = (qv ? rel_msg : rel_att);
#pragma unroll
  for (int i = 0; i < 16; ++i){
    int idx = tid + i*256;
    int j = idx & 31, k = idx >> 5;
    Ws[k*33 + j] = W[(size_t)k*T_HD + h*T_DK + j];
  }
#pragma unroll
  for (int i = 0; i < 20; ++i){
    int idx = tid + i*256;
    int bcol = idx & 31, a = (idx >> 5) & 31, r = idx >> 10;
    float wv = rel[((((size_t)l*T_R + r)*T_H + h)*T_DK + a)*T_DK + bcol];
    if (qv) As_[r*1152 + bcol*36 + a] = wv;
    else    As_[r*1152 + a*36 + bcol] = wv;
  }
  __syncthreads();
  int k = tid & 127, io = tid >> 7;
  float Wrow[32];
#pragma unroll
  for (int c = 0; c < 32; ++c) Wrow[c] = Ws[k*33 + c];
  for (int r = 0; r < T_R; ++r){
    float scale = qv ? 1.f : rel_pri[((size_t)l*T_R + r)*T_H + h] * isd;
#pragma unroll
    for (int i2 = 0; i2 < 16; ++i2){
      int o = i2*2 + io;
      const float4* ap = (const float4*)&As_[r*1152 + o*36];
      float acc = 0.f;
#pragma unroll
      for (int c4 = 0; c4 < 8; ++c4){
        float4 a4 = ap[c4];
        acc += Wrow[c4*4+0]*a4.x + Wrow[c4*4+1]*a4.y + Wrow[c4*4+2]*a4.z + Wrow[c4*4+3]*a4.w;
      }
      int col = 128 + qv*640 + r*128 + h*32 + o;
      Ball[((size_t)lt*NCOL + col)*T_HD + k] = f2bf(acc*scale);
    }
  }
}

// bf16 transposed weights for the FFN MFMA kernels
__global__ void k_prepw2(const float* __restrict__ adapt_w, const float* __restrict__ aw,
                         u16* __restrict__ adaptT, u16* __restrict__ awT)
{
  int idx = blockIdx.x*256 + threadIdx.x;
  if (idx < T_NT*T_HD*T_HD){
    int k = idx & 127, col = (idx >> 7) & 127, t = idx >> 14;
    adaptT[idx] = f2bf(adapt_w[((size_t)t*T_HD + k)*T_HD + col]);
  } else {
    int j = idx - T_NT*T_HD*T_HD;
    if (j >= T_L*T_NT*T_HD*T_HD) return;
    int k = j & 127, col = (j >> 7) & 127, lt = j >> 14;
    awT[j] = f2bf(aw[((size_t)lt*T_HD + perm_l(k))*T_HD + col]);
  }
}

// ---------------- fused per-type MFMA GEMM: h(bucket) -> {kB, qt, mtp}(bucket) ----------------
__global__ __launch_bounds__(256)
void k_qkvm(const float* __restrict__ X, const int* __restrict__ toff,
            const u16* __restrict__ Ball, const float* __restrict__ biasall,
            u16* __restrict__ kB, u16* __restrict__ qt, u16* __restrict__ mtp)
{
  __shared__ u16 As[64*128];
  int t = blockIdx.y;
  int z = blockIdx.z;
  int lo = toff[t], cnt = toff[t+1] - lo;
  int base = (int)blockIdx.x * 64;
  if (base >= cnt) return;
  int tid = threadIdx.x;
#pragma unroll
  for (int it = 0; it < 4; ++it){
    int chunk = tid + it*256;
    int row = chunk >> 4, c8 = (chunk & 15) << 3;
    uint4 o = make_uint4(0,0,0,0);
    if (base + row < cnt){
      const float* src = X + (size_t)(lo + base + row)*T_HD + c8;
      float4 f0 = *(const float4*)src;
      float4 f1 = *(const float4*)(src + 4);
      o.x = pk2(f0.x, f0.y);
      o.y = pk2(f0.z, f0.w);
      o.z = pk2(f1.x, f1.y);
      o.w = pk2(f1.z, f1.w);
    }
    int off16 = (row*128 + c8) ^ ((row & 7) << 3);
    *(uint4*)&As[off16] = o;
  }
  __syncthreads();

  int wid = tid >> 6, lane = tid & 63;
  int lr = lane & 15, lg = lane >> 4;
  bf8_t a[4][4];
#pragma unroll
  for (int rs = 0; rs < 4; ++rs)
#pragma unroll
    for (int kk = 0; kk < 4; ++kk){
      int row = rs*16 + lr;
      int off16 = (row*128 + kk*32 + lg*8) ^ ((row & 7) << 3);
      a[rs][kk] = *(const bf8_t*)&As[off16];
    }

  const u16* Bt = Ball + (size_t)t * NCOL * T_HD;
  const float* biast = biasall + (size_t)t * NCOL;

  int ci_end = z ? 44 : 22;
  for (int ci = z*22 + wid; ci < ci_end; ci += 4){
    int c0 = ci*2;
    int col0 = c0*16 + lr;
    const u16* bp0 = Bt + (size_t)col0*T_HD + lg*8;
    const u16* bp1 = bp0 + (size_t)16*T_HD;
    bf8_t b00 = *(const bf8_t*)(bp0);
    bf8_t b01 = *(const bf8_t*)(bp0 + 32);
    bf8_t b02 = *(const bf8_t*)(bp0 + 64);
    bf8_t b03 = *(const bf8_t*)(bp0 + 96);
    bf8_t b10 = *(const bf8_t*)(bp1);
    bf8_t b11 = *(const bf8_t*)(bp1 + 32);
    bf8_t b12 = *(const bf8_t*)(bp1 + 64);
    bf8_t b13 = *(const bf8_t*)(bp1 + 96);
    f4_t acc0[4], acc1[4];
#pragma unroll
    for (int rs = 0; rs < 4; ++rs){ acc0[rs] = (f4_t){0.f,0.f,0.f,0.f}; acc1[rs] = (f4_t){0.f,0.f,0.f,0.f}; }
#pragma unroll
    for (int rs = 0; rs < 4; ++rs){
      acc0[rs] = __builtin_amdgcn_mfma_f32_16x16x32_bf16(b00, a[rs][0], acc0[rs], 0, 0, 0);
      acc0[rs] = __builtin_amdgcn_mfma_f32_16x16x32_bf16(b01, a[rs][1], acc0[rs], 0, 0, 0);
      acc0[rs] = __builtin_amdgcn_mfma_f32_16x16x32_bf16(b02, a[rs][2], acc0[rs], 0, 0, 0);
      acc0[rs] = __builtin_amdgcn_mfma_f32_16x16x32_bf16(b03, a[rs][3], acc0[rs], 0, 0, 0);
      acc1[rs] = __builtin_amdgcn_mfma_f32_16x16x32_bf16(b10, a[rs][0], acc1[rs], 0, 0, 0);
      acc1[rs] = __builtin_amdgcn_mfma_f32_16x16x32_bf16(b11, a[rs][1], acc1[rs], 0, 0, 0);
      acc1[rs] = __builtin_amdgcn_mfma_f32_16x16x32_bf16(b12, a[rs][2], acc1[rs], 0, 0, 0);
      acc1[rs] = __builtin_amdgcn_mfma_f32_16x16x32_bf16(b13, a[rs][3], acc1[rs], 0, 0, 0);
    }
    float4 bias0 = *(const float4*)&biast[c0*16 + lg*4];
    float4 bias1 = *(const float4*)&biast[c0*16 + 16 + lg*4];
    int mco = ci*32 + lg*8;
    u16* dst; int cofs, stride;
    if (ci < 4)       { dst = kB;  cofs = mco;        stride = T_HD; }
    else if (ci < 24) { dst = qt;  cofs = mco - 128;  stride = T_R*T_HD; }
    else              { dst = mtp; cofs = mco - 768;  stride = T_R*T_HD; }
#pragma unroll
    for (int rs = 0; rs < 4; ++rs){
      int nl = rs*16 + lr;
      if (base + nl < cnt){
        uint4 o;
        o.x = pk2(acc0[rs][0] + bias0.x, acc0[rs][1] + bias0.y);
        o.y = pk2(acc0[rs][2] + bias0.z, acc0[rs][3] + bias0.w);
        o.z = pk2(acc1[rs][0] + bias1.x, acc1[rs][1] + bias1.y);
        o.w = pk2(acc1[rs][2] + bias1.z, acc1[rs][3] + bias1.w);
        *(uint4*)&dst[(size_t)(lo + base + nl)*stride + cofs] = o;
      }
    }
  }
}

// ---------------- MFMA FFN: adapt (MODE 1) and update (MODE 3) ----------------
template<int MODE, int GIN, int SOUT>
__global__ __launch_bounds__(256)
void k_ffn(const float* __restrict__ X, const int* __restrict__ tperm,
           const int* __restrict__ toff, const u16* __restrict__ WT,
           const float* __restrict__ Bi, float* __restrict__ outv,
           const float* __restrict__ h_in, const float* __restrict__ skipv)
{
  __shared__ u16 As[64*128];
  __shared__ int rows_s[64];
  int t = blockIdx.y;
  int lo = toff[t], cnt = toff[t+1] - lo;
  int base = (int)blockIdx.x * 64;
  if (base >= cnt) return;
  int tid = threadIdx.x;
  if (GIN || SOUT){
    if (tid < 64) rows_s[tid] = (base + tid < cnt) ? tperm[lo + base + tid] : 0;
    __syncthreads();
  }
#pragma unroll
  for (int it = 0; it < 4; ++it){
    int chunk = tid + it*256;
    int row = chunk >> 4, c8 = (chunk & 15) << 3;
    uint4 o = make_uint4(0,0,0,0);
    if (base + row < cnt){
      const float* src = GIN ? (X + (size_t)rows_s[row]*T_HD + c8)
                             : (X + (size_t)(lo + base + row)*T_HD + c8);
      float4 f0 = *(const float4*)src;
      float4 f1 = *(const float4*)(src + 4);
      if (MODE == 3){
        f0.x = gelu_f(f0.x); f0.y = gelu_f(f0.y); f0.z = gelu_f(f0.z); f0.w = gelu_f(f0.w);
        f1.x = gelu_f(f1.x); f1.y = gelu_f(f1.y); f1.z = gelu_f(f1.z); f1.w = gelu_f(f1.w);
      }
      o.x = pk2(f0.x, f0.y);
      o.y = pk2(f0.z, f0.w);
      o.z = pk2(f1.x, f1.y);
      o.w = pk2(f1.z, f1.w);
    }
    int off16 = (row*128 + c8) ^ ((row & 7) << 3);
    *(uint4*)&As[off16] = o;
  }
  __syncthreads();

  int wid = tid >> 6, lane = tid & 63;
  int lr = lane & 15, lg = lane >> 4;
  bf8_t a[4][4];
#pragma unroll
  for (int rs = 0; rs < 4; ++rs)
#pragma unroll
    for (int kk = 0; kk < 4; ++kk){
      int row = rs*16 + lr;
      int off16 = (row*128 + kk*32 + lg*8) ^ ((row & 7) << 3);
      a[rs][kk] = *(const bf8_t*)&As[off16];
    }

  const u16* Wt = WT + (size_t)t * T_HD * T_HD;
  float sk = 0.f;
  if (MODE == 3) sk = 1.f / (1.f + __expf(-skipv[t]));

  for (int c = wid; c < 8; c += 4){
    const u16* bp = Wt + (size_t)(c*16 + lr)*T_HD + lg*8;
    bf8_t b0 = *(const bf8_t*)(bp);
    bf8_t b1 = *(const bf8_t*)(bp + 32);
    bf8_t b2 = *(const bf8_t*)(bp + 64);
    bf8_t b3 = *(const bf8_t*)(bp + 96);
    f4_t acc[4];
#pragma unroll
    for (int rs = 0; rs < 4; ++rs) acc[rs] = (f4_t){0.f,0.f,0.f,0.f};
#pragma unroll
    for (int rs = 0; rs < 4; ++rs){
      acc[rs] = __builtin_amdgcn_mfma_f32_16x16x32_bf16(b0, a[rs][0], acc[rs], 0, 0, 0);
      acc[rs] = __builtin_amdgcn_mfma_f32_16x16x32_bf16(b1, a[rs][1], acc[rs], 0, 0, 0);
      acc[rs] = __builtin_amdgcn_mfma_f32_16x16x32_bf16(b2, a[rs][2], acc[rs], 0, 0, 0);
      acc[rs] = __builtin_amdgcn_mfma_f32_16x16x32_bf16(b3, a[rs][3], acc[rs], 0, 0, 0);
    }
    int cc = c*16 + lg*4;
    float4 bias4 = *(const float4*)&Bi[t*T_HD + cc];
#pragma unroll
    for (int rs = 0; rs < 4; ++rs){
      int nl = rs*16 + lr;
      if (base + nl < cnt){
        float4 vv;
        vv.x = acc[rs][0] + bias4.x;
        vv.y = acc[rs][1] + bias4.y;
        vv.z = acc[rs][2] + bias4.z;
        vv.w = acc[rs][3] + bias4.w;
        if (MODE == 1){
          vv.x = tanhf(vv.x); vv.y = tanhf(vv.y); vv.z = tanhf(vv.z); vv.w = tanhf(vv.w);
        }
        if (MODE == 3){
          float4 hr = *(const float4*)&h_in[(size_t)(lo + base + nl)*T_HD + cc];
          float osk = 1.f - sk;
          vv.x = vv.x*sk + hr.x*osk;
          vv.y = vv.y*sk + hr.y*osk;
          vv.z = vv.z*sk + hr.z*osk;
          vv.w = vv.w*sk + hr.w*osk;
        }
        size_t opos = SOUT ? (size_t)rows_s[nl] : (size_t)(lo + base + nl);
        *(float4*)&outv[opos*T_HD + cc] = vv;
      }
    }
  }
}

// ---------------- per-dst edge attention (single-state, deferred-max) ----------------
__global__ __launch_bounds__(256)
void k_edge_attn2(const u16* __restrict__ kB, const u16* __restrict__ qt,
                  const u16* __restrict__ mtp, const int* __restrict__ rp,
                  const int* __restrict__ packed, float* __restrict__ resb, int n)
{
  int lane = threadIdx.x & 63;
  int wid = (int)blockIdx.x * (blockDim.x >> 6) + (threadIdx.x >> 6);
  int nw = (int)gridDim.x * (blockDim.x >> 6);
  int l2 = lane << 1;
  for (int dst = wid; dst < n; dst += nw){
    int e0 = rp[dst], e1 = rp[dst+1];
    if (e0 == e1){
      *(float2*)&resb[(size_t)dst*T_HD + l2] = make_float2(0.f, 0.f);
      continue;
    }
    const u16* qrow = qt + (size_t)dst*(T_R*T_HD) + l2;
    float m = -1e30f, d = 0.f, a0 = 0.f, a1 = 0.f;
    int ei = e0;
    for (; ei + 1 < e1; ei += 2){
      int pka = packed[ei], pkb = packed[ei+1];
      int sa = pka & 131071, ra = pka >> 17;
      int sb = pkb & 131071, rb = pkb >> 17;
      unsigned ka  = *(const unsigned*)&kB[(sa << 7) + l2];
      unsigned kbv = *(const unsigned*)&kB[(sb << 7) + l2];
      unsigned qa = *(const unsigned*)&qrow[ra << 7];
      unsigned qb = *(const unsigned*)&qrow[rb << 7];
      unsigned ma = *(const unsigned*)&mtp[((sa*T_R + ra) << 7) + l2];
      unsigned mb = *(const unsigned*)&mtp[((sb*T_R + rb) << 7) + l2];
      float pa = blo(qa)*blo(ka) + bhi(qa)*bhi(ka);
      float pb = blo(qb)*blo(kbv) + bhi(qb)*bhi(kbv);
      pa += __shfl_xor(pa, 1);  pb += __shfl_xor(pb, 1);
      pa += __shfl_xor(pa, 2);  pb += __shfl_xor(pb, 2);
      pa += __shfl_xor(pa, 4);  pb += __shfl_xor(pb, 4);
      pa += __shfl_xor(pa, 8);  pb += __shfl_xor(pb, 8);
      float pmax = fmaxf(pa, pb);
      if (__any(pmax > m + 8.f)){
        float mn = fmaxf(m, pmax);
        float sc = __expf(m - mn);
        d *= sc; a0 *= sc; a1 *= sc;
        m = mn;
      }
      float wA = __expf(pa - m), wB = __expf(pb - m);
      d  += wA + wB;
      a0 += wA*blo(ma) + wB*blo(mb);
      a1 += wA*bhi(ma) + wB*bhi(mb);
    }
    if (ei < e1){
      int pka = packed[ei];
      int sa = pka & 131071, ra = pka >> 17;
      unsigned ka = *(const unsigned*)&kB[(sa << 7) + l2];
      unsigned qa = *(const unsigned*)&qrow[ra << 7];
      unsigned ma = *(const unsigned*)&mtp[((sa*T_R + ra) << 7) + l2];
      float pa = blo(qa)*blo(ka) + bhi(qa)*bhi(ka);
      pa += __shfl_xor(pa, 1);
      pa += __shfl_xor(pa, 2);
      pa += __shfl_xor(pa, 4);
      pa += __shfl_xor(pa, 8);
      if (__any(pa > m + 8.f)){
        float mn = fmaxf(m, pa);
        float sc = __expf(m - mn);
        d *= sc; a0 *= sc; a1 *= sc;
        m = mn;
      }
      float wA = __expf(pa - m);
      d  += wA;
      a0 += wA*blo(ma);
      a1 += wA*bhi(ma);
    }
    float inv = 1.f / fmaxf(d, 1e-9f);
    *(float2*)&resb[(size_t)dst*T_HD + l2] = make_float2(a0*inv, a1*inv);
  }
}

extern "C" void kernel_launch(void* const* d_in, const int* in_sizes, int n_in,
                              void* d_out, int out_size, void* d_ws, size_t ws_size,
                              hipStream_t stream)
{
  const float* node_feature = (const float*)d_in[0];
  const int* node_type    = (const int*)d_in[1];
  const int* edge_index   = (const int*)d_in[3];
  const int* edge_type    = (const int*)d_in[4];
  const float* adapt_w = (const float*)d_in[5];
  const float* adapt_b = (const float*)d_in[6];
  const float* kw = (const float*)d_in[7];
  const float* kb = (const float*)d_in[8];
  const float* qw = (const float*)d_in[9];
  const float* qb = (const float*)d_in[10];
  const float* vw = (const float*)d_in[11];
  const float* vb = (const float*)d_in[12];
  const float* aw = (const float*)d_in[13];
  const float* ab = (const float*)d_in[14];
  const float* rel_pri = (const float*)d_in[15];
  const float* rel_att = (const float*)d_in[16];
  const float* rel_msg = (const float*)d_in[17];
  const float* skipp   = (const float*)d_in[18];

  const int N = in_sizes[1];
  const int E = in_sizes[4];
  const int* srcp = edge_index;
  const int* dstp = edge_index + E;

  char* p = (char*)d_ws;
  auto take = [&](size_t bytes)->char*{
    char* r = p; p += (bytes + 255) & ~(size_t)255; return r;
  };
  float* h0   = (float*)take((size_t)N*T_HD*4);
  float* resb = (float*)take((size_t)N*T_HD*4);
  u16*  kB    = (u16*) take((size_t)N*T_HD*2);
  u16*  qt    = (u16*) take((size_t)N*T_R*T_HD*2);
  u16*  mtp   = (u16*) take((size_t)N*T_R*T_HD*2);
  u16*  Ball  = (u16*) take((size_t)T_L*T_NT*NCOL*T_HD*2);
  float* biasall = (float*)take((size_t)T_L*T_NT*NCOL*4);
  u16*  adaptT = (u16*)take((size_t)T_NT*T_HD*T_HD*2);
  u16*  awT    = (u16*)take((size_t)T_L*T_NT*T_HD*T_HD*2);
  int* degp   = (int*) take((size_t)N*16*4);
  int* rp     = (int*) take(((size_t)N+1)*4);
  int* rank   = (int*) take((size_t)E*4);
  int* packed = (int*) take((size_t)E*4);
  int* tcnt   = (int*) take(256);
  int* toff   = (int*) take(256);
  int* tcur   = (int*) take(256);
  int* bsum   = (int*) take(1024);
  int* tperm  = (int*) take((size_t)N*4);
  int* iperm  = (int*) take((size_t)N*4);

  hipMemsetAsync(degp, 0, (size_t)N*16*4, stream);
  hipMemsetAsync(tcnt, 0, 256, stream);

  int nb_n4 = (N + 1023)/1024, nb_e = (E + 255)/256;
  int nb_s  = (N + 255)/256;
  k_hist4<<<nb_n4, 256, 0, stream>>>(node_type, tcnt, N);
  k_toff<<<1, 64, 0, stream>>>(tcnt, toff, tcur);
  k_scatter2<<<nb_n4, 256, 0, stream>>>(node_type, tcur, tperm, iperm, N);
  k_deg<<<nb_e, 256, 0, stream>>>(dstp, iperm, degp, rank, E);
  k_scanA<<<nb_s, 256, 0, stream>>>(degp, rp, bsum, N);
  k_scanB<<<1, 1024, 0, stream>>>(bsum, nb_s);
  k_scanC<<<nb_s, 256, 0, stream>>>(rp, bsum, N, E);
  k_fill2<<<nb_e, 256, 0, stream>>>(srcp, dstp, edge_type, iperm, rp, rank, packed, E);

  int misc_total = T_L*T_NT*T_HD*T_HD + T_L*T_NT*1280;
  k_prepmisc<<<(misc_total + 255)/256, 256, 0, stream>>>(
      kw, kb, qb, vb, rel_att, rel_msg, rel_pri, Ball, biasall);
  k_prepqv<<<dim3(8, T_NT, T_L), 256, 0, stream>>>(
      qw, vw, rel_att, rel_msg, rel_pri, Ball);
  int w2_total = T_NT*T_HD*T_HD + T_L*T_NT*T_HD*T_HD;
  k_prepw2<<<(w2_total + 255)/256, 256, 0, stream>>>(adapt_w, aw, adaptT, awT);

  dim3 gg((N + 63)/64, T_NT);
  dim3 gq((N + 63)/64, T_NT, 2);
  k_ffn<1,1,0><<<gg, 256, 0, stream>>>(node_feature, tperm, toff, adaptT, adapt_b, h0, nullptr, nullptr);

  for (int l = 0; l < T_L; ++l){
    size_t bo = (size_t)l * T_NT * T_HD;
    k_qkvm<<<gq, 256, 0, stream>>>(h0, toff,
        Ball + (size_t)l*T_NT*NCOL*T_HD, biasall + (size_t)l*T_NT*NCOL,
        kB, qt, mtp);
    k_edge_attn2<<<2048, 256, 0, stream>>>(kB, qt, mtp, rp, packed, resb, N);
    if (l == T_L - 1)
      k_ffn<3,0,1><<<gg, 256, 0, stream>>>(resb, tperm, toff,
          awT + (size_t)l*T_NT*T_HD*T_HD, ab + bo, (float*)d_out, h0, skipp + l*T_NT);
    else
      k_ffn<3,0,0><<<gg, 256, 0, stream>>>(resb, tperm, toff,
          awT + (size_t)l*T_NT*T_HD*T_HD, ab + bo, h0, h0, skipp + l*T_NT);
  }
}